// Round 8
// baseline (23628.999 us; speedup 1.0000x reference)
//
#include <hip/hip_runtime.h>
#include <hip/hip_fp16.h>

#define NN 4096
#define TOLF 1e-9f
#define MAX_ITER 100
#define RPB 8      // rows per block in k_iter  -> 512 blocks
#define RPBF 4     // rows per block in k_final -> 1024 blocks

__device__ __forceinline__ float fastrcp(float x) {
    return __builtin_amdgcn_rcpf(x);   // v_rcp_f32, ~1e-6 rel err
}

union H2U { __half2 h; unsigned int u; };

// Convert 16 packed halves (2x uint4) to 16 floats (fully unrolled -> regs)
__device__ __forceinline__ void cvt16(const uint4* k, float* f) {
#pragma unroll
    for (int q = 0; q < 2; ++q) {
        const unsigned int* w = (const unsigned int*)&k[q];
#pragma unroll
        for (int m = 0; m < 4; ++m) {
            H2U hu; hu.u = w[m];
            float2 d = __half22float2(hu.h);
            f[q * 8 + 2 * m]     = d.x;
            f[q * 8 + 2 * m + 1] = d.y;
        }
    }
}

// Kh = (half)exp(-10*C); zero buf1 (first atomic target) and loss
__global__ __launch_bounds__(256) void k_init(const float* __restrict__ C,
                                              __half* __restrict__ Kh,
                                              float* __restrict__ buf1,
                                              float* __restrict__ loss) {
    int tid = blockIdx.x * 256 + threadIdx.x;
    const float4* C4 = (const float4*)C;
    uint4* K4 = (uint4*)Kh;
    const int total8 = NN * NN / 8;
    for (int i = tid; i < total8; i += gridDim.x * 256) {
        float4 a = C4[2 * i];
        float4 b = C4[2 * i + 1];
        H2U h0, h1, h2, h3;
        h0.h = __floats2half2_rn(__expf(-10.f * a.x), __expf(-10.f * a.y));
        h1.h = __floats2half2_rn(__expf(-10.f * a.z), __expf(-10.f * a.w));
        h2.h = __floats2half2_rn(__expf(-10.f * b.x), __expf(-10.f * b.y));
        h3.h = __floats2half2_rn(__expf(-10.f * b.z), __expf(-10.f * b.w));
        uint4 o; o.x = h0.u; o.y = h1.u; o.z = h2.u; o.w = h3.u;
        K4[i] = o;
    }
    if (tid < NN) buf1[tid] = 0.f;
    if (tid == 0) *loss = 0.f;
}

// One Sinkhorn iteration, fused:
//   v_j = nu_j / (vprev_j + tol)            (regs, per-thread 16 columns)
//   u_i = mu_i / (K[i,:].v + tol)           (rows r0..r0+7, block reduction)
//   vnext_j += sum_i u_i*K[i,j]             (same K registers, global atomics)
//   vzero[:] = 0                            (third buffer, race-free by 3-buffering)
__global__ __launch_bounds__(256, 2) void k_iter(const __half* __restrict__ Kh,
                                                 const float* __restrict__ mu,
                                                 const float* __restrict__ nu,
                                                 const float* __restrict__ vprev,
                                                 float* __restrict__ vnext,
                                                 float* __restrict__ vzero,
                                                 float* __restrict__ uG,
                                                 int first) {
    const int t  = threadIdx.x;
    const int b  = blockIdx.x;
    const int r0 = b * RPB;
    const int c0 = t * 16;          // this thread's 16 contiguous columns

    __shared__ float wsum[4][RPB];
    __shared__ float ush[RPB];

    // zero the buffer that iteration t+1 will atomically accumulate into
    if (b < 16) vzero[b * 256 + t] = 0.f;

    // v in registers
    float v[16];
    if (first) {
#pragma unroll
        for (int s = 0; s < 16; ++s) v[s] = 1.f;
    } else {
        const float4* nu4 = (const float4*)(nu + c0);
        const float4* vp4 = (const float4*)(vprev + c0);
#pragma unroll
        for (int q = 0; q < 4; ++q) {
            float4 n = nu4[q];
            float4 p = vp4[q];
            v[4 * q + 0] = n.x * fastrcp(p.x + TOLF);
            v[4 * q + 1] = n.y * fastrcp(p.y + TOLF);
            v[4 * q + 2] = n.z * fastrcp(p.z + TOLF);
            v[4 * q + 3] = n.w * fastrcp(p.w + TOLF);
        }
    }

    // load 8 K rows (16 halves each) once
    uint4 kr[RPB][2];
#pragma unroll
    for (int r = 0; r < RPB; ++r) {
        const uint4* rowp = (const uint4*)(Kh + (size_t)(r0 + r) * NN + c0);
        kr[r][0] = rowp[0];
        kr[r][1] = rowp[1];
    }

    // per-thread partial dots
    float part[RPB];
#pragma unroll
    for (int r = 0; r < RPB; ++r) {
        float f[16];
        cvt16(kr[r], f);
        float acc = 0.f;
#pragma unroll
        for (int s = 0; s < 16; ++s) acc += f[s] * v[s];
        part[r] = acc;
    }

    // wave64 butterfly reduce each row partial
#pragma unroll
    for (int r = 0; r < RPB; ++r) {
#pragma unroll
        for (int off = 32; off > 0; off >>= 1)
            part[r] += __shfl_xor(part[r], off);
    }
    const int lane = t & 63, wid = t >> 6;
    if (lane == 0) {
#pragma unroll
        for (int r = 0; r < RPB; ++r) wsum[wid][r] = part[r];
    }
    __syncthreads();
    if (t < RPB) {
        float s  = wsum[0][t] + wsum[1][t] + wsum[2][t] + wsum[3][t];
        float ur = mu[r0 + t] * fastrcp(s + TOLF);
        ush[t] = ur;
        uG[r0 + t] = ur;
    }
    __syncthreads();

    // column accumulation with the SAME K registers
    float acc[16];
#pragma unroll
    for (int s = 0; s < 16; ++s) acc[s] = 0.f;
#pragma unroll
    for (int r = 0; r < RPB; ++r) {
        float ur = ush[r];
        float f[16];
        cvt16(kr[r], f);
#pragma unroll
        for (int s = 0; s < 16; ++s) acc[s] += ur * f[s];
    }
#pragma unroll
    for (int s = 0; s < 16; ++s) atomicAdd(&vnext[c0 + s], acc[s]);
}

// P[i][j] = u_i * exp(-10*C_ij) * v_j  (fp32 recompute from C); loss = sum P*|mu_i-nu_j|
__global__ __launch_bounds__(256) void k_final(const float* __restrict__ C,
                                               const float* __restrict__ mu,
                                               const float* __restrict__ nu,
                                               const float* __restrict__ uG,
                                               const float* __restrict__ vlast,
                                               float* __restrict__ P,
                                               float* __restrict__ loss) {
    const int t  = threadIdx.x;
    const int b  = blockIdx.x;
    const int r0 = b * RPBF;
    const int c0 = t * 16;

    __shared__ float ls[4];

    float v[16], nuv[16];
    const float4* nu4 = (const float4*)(nu + c0);
    const float4* vl4 = (const float4*)(vlast + c0);
#pragma unroll
    for (int q = 0; q < 4; ++q) {
        float4 n = nu4[q];
        float4 p = vl4[q];
        nuv[4 * q + 0] = n.x; nuv[4 * q + 1] = n.y;
        nuv[4 * q + 2] = n.z; nuv[4 * q + 3] = n.w;
        v[4 * q + 0] = n.x * fastrcp(p.x + TOLF);
        v[4 * q + 1] = n.y * fastrcp(p.y + TOLF);
        v[4 * q + 2] = n.z * fastrcp(p.z + TOLF);
        v[4 * q + 3] = n.w * fastrcp(p.w + TOLF);
    }

    float lacc = 0.f;
#pragma unroll
    for (int r = 0; r < RPBF; ++r) {
        const float ur  = uG[r0 + r];
        const float mur = mu[r0 + r];
        const float4* Cr = (const float4*)(C + (size_t)(r0 + r) * NN + c0);
        float4* Pr       = (float4*)(P + (size_t)(r0 + r) * NN + c0);
#pragma unroll
        for (int q = 0; q < 4; ++q) {
            float4 c = Cr[q];
            float4 p;
            p.x = ur * __expf(-10.f * c.x) * v[4 * q + 0];
            p.y = ur * __expf(-10.f * c.y) * v[4 * q + 1];
            p.z = ur * __expf(-10.f * c.z) * v[4 * q + 2];
            p.w = ur * __expf(-10.f * c.w) * v[4 * q + 3];
            Pr[q] = p;
            lacc += p.x * fabsf(mur - nuv[4 * q + 0]) +
                    p.y * fabsf(mur - nuv[4 * q + 1]) +
                    p.z * fabsf(mur - nuv[4 * q + 2]) +
                    p.w * fabsf(mur - nuv[4 * q + 3]);
        }
    }
#pragma unroll
    for (int off = 32; off > 0; off >>= 1) lacc += __shfl_xor(lacc, off);
    const int lane = t & 63, wid = t >> 6;
    if (lane == 0) ls[wid] = lacc;
    __syncthreads();
    if (t == 0) atomicAdd(loss, ls[0] + ls[1] + ls[2] + ls[3]);
}

extern "C" void kernel_launch(void* const* d_in, const int* in_sizes, int n_in,
                              void* d_out, int out_size, void* d_ws, size_t ws_size,
                              hipStream_t stream) {
    const float* mu = (const float*)d_in[0];
    const float* nu = (const float*)d_in[1];
    const float* C  = (const float*)d_in[2];

    float* P    = (float*)d_out;
    float* loss = P + (size_t)NN * NN;
    __half* Kh  = (__half*)d_out;    // fp16 K in first 32 MiB of P region;
                                     // k_final never reads Kh, so the P
                                     // overwrite at the end is race-free.

    float* ws  = (float*)d_ws;
    float* uG  = ws;                 // 4096
    float* b0  = ws + NN;            // vacc triple buffer
    float* b1  = ws + 2 * NN;
    float* b2  = ws + 3 * NN;
    float* buf[3] = {b0, b1, b2};

    k_init<<<2048, 256, 0, stream>>>(C, Kh, b1, loss);

    for (int t = 0; t < MAX_ITER; ++t) {
        k_iter<<<NN / RPB, 256, 0, stream>>>(Kh, mu, nu,
                                             buf[t % 3],        // read
                                             buf[(t + 1) % 3],  // accumulate (pre-zeroed)
                                             buf[(t + 2) % 3],  // zero for next iter
                                             uG, t == 0 ? 1 : 0);
    }

    // final v comes from buf[(99+1)%3] = buf[1]
    k_final<<<NN / RPBF, 256, 0, stream>>>(C, mu, nu, uG, buf[MAX_ITER % 3], P, loss);
}

// Round 9
// 1684.218 us; speedup vs baseline: 14.0297x; 14.0297x over previous
//
#include <hip/hip_runtime.h>
#include <hip/hip_fp16.h>

#define NN 4096
#define TOLF 1e-9f
#define MAX_ITER 100
#define RPB 8      // rows per block in k_u     -> 512 blocks
#define CPB 64     // cols per block in k_col
#define PCH 8      // row-chunks in k_col       -> 64*8 = 512 blocks, 512 rows/chunk
#define RPBF 4     // rows per block in k_final -> 1024 blocks

__device__ __forceinline__ float fastrcp(float x) {
    return __builtin_amdgcn_rcpf(x);   // v_rcp_f32, ~1e-6 rel err
}

union H2U { __half2 h; unsigned int u; };

// Convert 16 packed halves (2x uint4) to 16 floats (fully unrolled -> regs)
__device__ __forceinline__ void cvt16(const uint4* k, float* f) {
#pragma unroll
    for (int q = 0; q < 2; ++q) {
        const unsigned int* w = (const unsigned int*)&k[q];
#pragma unroll
        for (int m = 0; m < 4; ++m) {
            H2U hu; hu.u = w[m];
            float2 d = __half22float2(hu.h);
            f[q * 8 + 2 * m]     = d.x;
            f[q * 8 + 2 * m + 1] = d.y;
        }
    }
}

// Kh = (half)exp(-10*C); zero buf1 (first atomic target) and loss
__global__ __launch_bounds__(256) void k_init(const float* __restrict__ C,
                                              __half* __restrict__ Kh,
                                              float* __restrict__ buf1,
                                              float* __restrict__ loss) {
    int tid = blockIdx.x * 256 + threadIdx.x;
    const float4* C4 = (const float4*)C;
    uint4* K4 = (uint4*)Kh;
    const int total8 = NN * NN / 8;
    for (int i = tid; i < total8; i += gridDim.x * 256) {
        float4 a = C4[2 * i];
        float4 b = C4[2 * i + 1];
        H2U h0, h1, h2, h3;
        h0.h = __floats2half2_rn(__expf(-10.f * a.x), __expf(-10.f * a.y));
        h1.h = __floats2half2_rn(__expf(-10.f * a.z), __expf(-10.f * a.w));
        h2.h = __floats2half2_rn(__expf(-10.f * b.x), __expf(-10.f * b.y));
        h3.h = __floats2half2_rn(__expf(-10.f * b.z), __expf(-10.f * b.w));
        uint4 o; o.x = h0.u; o.y = h1.u; o.z = h2.u; o.w = h3.u;
        K4[i] = o;
    }
    if (tid < NN) buf1[tid] = 0.f;
    if (tid == 0) *loss = 0.f;
}

// Row phase: u_i = mu_i / (K[i,:].v + tol), v_j = nu_j/(vacc_j + tol) in regs.
// 512 blocks x 256 thr, 8 rows/block, thread owns 16 contiguous columns.
__global__ __launch_bounds__(256, 4) void k_u(const __half* __restrict__ Kh,
                                              const float* __restrict__ mu,
                                              const float* __restrict__ nu,
                                              const float* __restrict__ vacc,
                                              float* __restrict__ uG,
                                              int first) {
    const int t  = threadIdx.x;
    const int b  = blockIdx.x;
    const int r0 = b * RPB;
    const int c0 = t * 16;

    __shared__ float wsum[4][RPB];

    // v for this thread's 16 columns
    float v[16];
    if (first) {
#pragma unroll
        for (int s = 0; s < 16; ++s) v[s] = 1.f;
    } else {
        const float4* nu4 = (const float4*)(nu + c0);
        const float4* va4 = (const float4*)(vacc + c0);
#pragma unroll
        for (int q = 0; q < 4; ++q) {
            float4 n = nu4[q];
            float4 p = va4[q];
            v[4 * q + 0] = n.x * fastrcp(p.x + TOLF);
            v[4 * q + 1] = n.y * fastrcp(p.y + TOLF);
            v[4 * q + 2] = n.z * fastrcp(p.z + TOLF);
            v[4 * q + 3] = n.w * fastrcp(p.w + TOLF);
        }
    }

    // per-row load + dot (one pass, low register pressure)
    float part[RPB];
#pragma unroll
    for (int r = 0; r < RPB; ++r) {
        const uint4* rowp = (const uint4*)(Kh + (size_t)(r0 + r) * NN + c0);
        uint4 kr[2];
        kr[0] = rowp[0];
        kr[1] = rowp[1];
        float f[16];
        cvt16(kr, f);
        float acc = 0.f;
#pragma unroll
        for (int s = 0; s < 16; ++s) acc += f[s] * v[s];
        part[r] = acc;
    }

    // wave64 butterfly, then cross-wave via LDS
#pragma unroll
    for (int r = 0; r < RPB; ++r) {
#pragma unroll
        for (int off = 32; off > 0; off >>= 1)
            part[r] += __shfl_xor(part[r], off);
    }
    const int lane = t & 63, wid = t >> 6;
    if (lane == 0) {
#pragma unroll
        for (int r = 0; r < RPB; ++r) wsum[wid][r] = part[r];
    }
    __syncthreads();
    if (t < RPB) {
        float s = wsum[0][t] + wsum[1][t] + wsum[2][t] + wsum[3][t];
        uG[r0 + t] = mu[r0 + t] * fastrcp(s + TOLF);
    }
}

// Column phase: vnext_j += sum_i u_i * K[i,j].
// Grid 512 = 64 col-groups x 8 row-chunks. Block: 64 cols x 512 rows.
// Thread t: col = g*64+(t&63), rows (t>>6)+4k. Wave reads 64 consecutive
// halves per row = 128 B coalesced. Block-internal LDS reduce ->
// ONE atomicAdd per (col, chunk): 32K atomics/iter at depth 8 (vs 2.1M @ 512).
// Also zeroes the t+2 buffer (triple-buffer rotation, race-free).
__global__ __launch_bounds__(256) void k_col(const __half* __restrict__ Kh,
                                             const float* __restrict__ uG,
                                             float* __restrict__ vnext,
                                             float* __restrict__ vzero) {
    const int t = threadIdx.x;
    const int g = blockIdx.x & 63;    // col group
    const int p = blockIdx.x >> 6;    // row chunk
    const int col   = g * CPB + (t & 63);
    const int rbase = p * (NN / PCH); // 512 rows per chunk

    __shared__ float ush[NN / PCH];
    __shared__ float red[4][CPB];

    if (p == 0 && t < CPB) vzero[g * CPB + t] = 0.f;

    if (t < 128) ((float4*)ush)[t] = ((const float4*)(uG + rbase))[t];
    __syncthreads();

    const __half* kp = Kh + (size_t)(rbase + (t >> 6)) * NN + col;
    int rl = t >> 6;
    float acc = 0.f;
#pragma unroll 8
    for (int k = 0; k < 128; ++k) {
        acc += __half2float(*kp) * ush[rl + 4 * k];
        kp += (size_t)4 * NN;
    }
    red[t >> 6][t & 63] = acc;
    __syncthreads();
    if (t < CPB) {
        float s = red[0][t] + red[1][t] + red[2][t] + red[3][t];
        atomicAdd(&vnext[g * CPB + t], s);
    }
}

// P[i][j] = u_i * exp(-10*C_ij) * v_j  (fp32 recompute from C); loss = sum P*|mu_i-nu_j|
__global__ __launch_bounds__(256) void k_final(const float* __restrict__ C,
                                               const float* __restrict__ mu,
                                               const float* __restrict__ nu,
                                               const float* __restrict__ uG,
                                               const float* __restrict__ vlast,
                                               float* __restrict__ P,
                                               float* __restrict__ loss) {
    const int t  = threadIdx.x;
    const int b  = blockIdx.x;
    const int r0 = b * RPBF;
    const int c0 = t * 16;

    __shared__ float ls[4];

    float v[16], nuv[16];
    const float4* nu4 = (const float4*)(nu + c0);
    const float4* vl4 = (const float4*)(vlast + c0);
#pragma unroll
    for (int q = 0; q < 4; ++q) {
        float4 n = nu4[q];
        float4 p = vl4[q];
        nuv[4 * q + 0] = n.x; nuv[4 * q + 1] = n.y;
        nuv[4 * q + 2] = n.z; nuv[4 * q + 3] = n.w;
        v[4 * q + 0] = n.x * fastrcp(p.x + TOLF);
        v[4 * q + 1] = n.y * fastrcp(p.y + TOLF);
        v[4 * q + 2] = n.z * fastrcp(p.z + TOLF);
        v[4 * q + 3] = n.w * fastrcp(p.w + TOLF);
    }

    float lacc = 0.f;
#pragma unroll
    for (int r = 0; r < RPBF; ++r) {
        const float ur  = uG[r0 + r];
        const float mur = mu[r0 + r];
        const float4* Cr = (const float4*)(C + (size_t)(r0 + r) * NN + c0);
        float4* Pr       = (float4*)(P + (size_t)(r0 + r) * NN + c0);
#pragma unroll
        for (int q = 0; q < 4; ++q) {
            float4 c = Cr[q];
            float4 p;
            p.x = ur * __expf(-10.f * c.x) * v[4 * q + 0];
            p.y = ur * __expf(-10.f * c.y) * v[4 * q + 1];
            p.z = ur * __expf(-10.f * c.z) * v[4 * q + 2];
            p.w = ur * __expf(-10.f * c.w) * v[4 * q + 3];
            Pr[q] = p;
            lacc += p.x * fabsf(mur - nuv[4 * q + 0]) +
                    p.y * fabsf(mur - nuv[4 * q + 1]) +
                    p.z * fabsf(mur - nuv[4 * q + 2]) +
                    p.w * fabsf(mur - nuv[4 * q + 3]);
        }
    }
#pragma unroll
    for (int off = 32; off > 0; off >>= 1) lacc += __shfl_xor(lacc, off);
    const int lane = t & 63, wid = t >> 6;
    if (lane == 0) ls[wid] = lacc;
    __syncthreads();
    if (t == 0) atomicAdd(loss, ls[0] + ls[1] + ls[2] + ls[3]);
}

extern "C" void kernel_launch(void* const* d_in, const int* in_sizes, int n_in,
                              void* d_out, int out_size, void* d_ws, size_t ws_size,
                              hipStream_t stream) {
    const float* mu = (const float*)d_in[0];
    const float* nu = (const float*)d_in[1];
    const float* C  = (const float*)d_in[2];

    float* P    = (float*)d_out;
    float* loss = P + (size_t)NN * NN;
    __half* Kh  = (__half*)d_out;    // fp16 K in first 32 MiB of P region;
                                     // k_final never reads Kh -> overwrite safe.

    float* ws  = (float*)d_ws;
    float* uG  = ws;                 // 4096
    float* b0  = ws + NN;            // vacc triple buffer
    float* b1  = ws + 2 * NN;
    float* b2  = ws + 3 * NN;
    float* buf[3] = {b0, b1, b2};

    k_init<<<2048, 256, 0, stream>>>(C, Kh, b1, loss);

    for (int t = 0; t < MAX_ITER; ++t) {
        // A(t): u from vacc = buf[t%3];  B(t): accumulate buf[(t+1)%3] (pre-zeroed),
        // zero buf[(t+2)%3] (untouched this iteration -> race-free).
        k_u  <<<NN / RPB, 256, 0, stream>>>(Kh, mu, nu, buf[t % 3], uG, t == 0 ? 1 : 0);
        k_col<<<CPB * PCH, 256, 0, stream>>>(Kh, uG, buf[(t + 1) % 3], buf[(t + 2) % 3]);
    }

    // final v comes from buf[(99+1)%3] = buf[1]
    k_final<<<NN / RPBF, 256, 0, stream>>>(C, mu, nu, uG, buf[MAX_ITER % 3], P, loss);
}